// Round 1
// baseline (658.152 us; speedup 1.0000x reference)
//
#include <hip/hip_runtime.h>
#include <math.h>

#define Bn 64
#define Hn 1024
#define BH (Bn * Hn)   // 65536

// ---------------------------------------------------------------------------
// Kernel 1: six skinny GEMMs  out[b,n] = act( sum_k A[b,k]*W[k,n] + bias[n] )
//   g=0,1,2 : A = concat(x, h_prev) (K=2048), act = sigmoid  -> i_t, f_t, o_t
//   g=3,4   : A = x (K=1024)                               -> k_t, v_t
//   g=5     : A = h_prev (K=1024)                          -> q_t
// Block: 256 threads = 4 waves. n-tile = 64 cols (t&63), each thread owns
// 4 consecutive B-rows (bg = t>>6 picks 4 of 16 rows in this block's b-tile).
// A tile staged in LDS; within a wave all lanes read the same A element
// (hardware broadcast, conflict-free).
// ---------------------------------------------------------------------------
__global__ __launch_bounds__(256) void gates_gemm(
    const float* __restrict__ x, const float* __restrict__ h_prev,
    const float* __restrict__ Wi, const float* __restrict__ bi,
    const float* __restrict__ Wf, const float* __restrict__ bf,
    const float* __restrict__ Wo, const float* __restrict__ bo,
    const float* __restrict__ Wk, const float* __restrict__ bk,
    const float* __restrict__ Wv, const float* __restrict__ bv,
    const float* __restrict__ Wq, const float* __restrict__ bq,
    float* __restrict__ ws)
{
    const int g = blockIdx.z;
    const float* A0;
    const float* A1 = nullptr;
    const float* Wm;
    const float* bias;
    float* outp;
    int K, act;
    switch (g) {
        case 0: A0 = x; A1 = h_prev; Wm = Wi; bias = bi; outp = ws + 0 * BH; K = 2048; act = 1; break;
        case 1: A0 = x; A1 = h_prev; Wm = Wf; bias = bf; outp = ws + 1 * BH; K = 2048; act = 1; break;
        case 2: A0 = x; A1 = h_prev; Wm = Wo; bias = bo; outp = ws + 2 * BH; K = 2048; act = 1; break;
        case 3: A0 = x;              Wm = Wk; bias = bk; outp = ws + 3 * BH; K = 1024; act = 0; break;
        case 4: A0 = x;              Wm = Wv; bias = bv; outp = ws + 4 * BH; K = 1024; act = 0; break;
        default:A0 = h_prev;         Wm = Wq; bias = bq; outp = ws + 5 * BH; K = 1024; act = 0; break;
    }

    __shared__ float A_lds[16][64];

    const int t  = threadIdx.x;
    const int n  = (blockIdx.x << 6) + (t & 63);   // global output column
    const int bg = t >> 6;                          // 0..3 -> which 4-row group
    const int rb = bg * 4;                          // row base within b-tile
    const int btile = blockIdx.y * 16;              // 16 rows of B per block

    float acc0 = 0.f, acc1 = 0.f, acc2 = 0.f, acc3 = 0.f;

    for (int k0 = 0; k0 < K; k0 += 64) {
        const float* Ab = (k0 < 1024) ? A0 : A1;
        const int kloc = k0 & 1023;
        __syncthreads();
        {   // cooperative load: 16 rows x 64 k-cols
            const int r = t >> 4;           // 0..15
            const int c = (t & 15) << 2;    // 0..60 step 4
            *(float4*)&A_lds[r][c] =
                *(const float4*)&Ab[(size_t)(btile + r) * 1024 + kloc + c];
        }
        __syncthreads();
        #pragma unroll
        for (int kk = 0; kk < 64; kk += 4) {
            const float4 a0 = *(const float4*)&A_lds[rb + 0][kk];
            const float4 a1 = *(const float4*)&A_lds[rb + 1][kk];
            const float4 a2 = *(const float4*)&A_lds[rb + 2][kk];
            const float4 a3 = *(const float4*)&A_lds[rb + 3][kk];
            const float w0 = Wm[(size_t)(k0 + kk + 0) * 1024 + n];
            const float w1 = Wm[(size_t)(k0 + kk + 1) * 1024 + n];
            const float w2 = Wm[(size_t)(k0 + kk + 2) * 1024 + n];
            const float w3 = Wm[(size_t)(k0 + kk + 3) * 1024 + n];
            acc0 += a0.x * w0; acc0 += a0.y * w1; acc0 += a0.z * w2; acc0 += a0.w * w3;
            acc1 += a1.x * w0; acc1 += a1.y * w1; acc1 += a1.z * w2; acc1 += a1.w * w3;
            acc2 += a2.x * w0; acc2 += a2.y * w1; acc2 += a2.z * w2; acc2 += a2.w * w3;
            acc3 += a3.x * w0; acc3 += a3.y * w1; acc3 += a3.z * w2; acc3 += a3.w * w3;
        }
    }

    const float bb = bias[n];
    float v0 = acc0 + bb, v1 = acc1 + bb, v2 = acc2 + bb, v3 = acc3 + bb;
    if (act) {
        v0 = 1.f / (1.f + expf(-v0));
        v1 = 1.f / (1.f + expf(-v1));
        v2 = 1.f / (1.f + expf(-v2));
        v3 = 1.f / (1.f + expf(-v3));
    }
    const int orow = btile + rb;
    outp[(size_t)(orow + 0) * 1024 + n] = v0;
    outp[(size_t)(orow + 1) * 1024 + n] = v1;
    outp[(size_t)(orow + 2) * 1024 + n] = v2;
    outp[(size_t)(orow + 3) * 1024 + n] = v3;
}

// ---------------------------------------------------------------------------
// Kernel 2: m = k_t @ We + be ;  n_t = f_t * n_prev + i_t * exp(m)
// Same blocking as gates_gemm (single GEMM, K=1024).
// ---------------------------------------------------------------------------
__global__ __launch_bounds__(256) void ngate_gemm(
    const float* __restrict__ We, const float* __restrict__ be,
    const float* __restrict__ n_prev, const float* __restrict__ ws,
    float* __restrict__ n_out)
{
    const float* kt = ws + 3 * BH;
    const float* it = ws + 0 * BH;
    const float* ft = ws + 1 * BH;

    __shared__ float A_lds[16][64];

    const int t  = threadIdx.x;
    const int n  = (blockIdx.x << 6) + (t & 63);
    const int bg = t >> 6;
    const int rb = bg * 4;
    const int btile = blockIdx.y * 16;

    float acc0 = 0.f, acc1 = 0.f, acc2 = 0.f, acc3 = 0.f;

    for (int k0 = 0; k0 < 1024; k0 += 64) {
        __syncthreads();
        {
            const int r = t >> 4;
            const int c = (t & 15) << 2;
            *(float4*)&A_lds[r][c] =
                *(const float4*)&kt[(size_t)(btile + r) * 1024 + k0 + c];
        }
        __syncthreads();
        #pragma unroll
        for (int kk = 0; kk < 64; kk += 4) {
            const float4 a0 = *(const float4*)&A_lds[rb + 0][kk];
            const float4 a1 = *(const float4*)&A_lds[rb + 1][kk];
            const float4 a2 = *(const float4*)&A_lds[rb + 2][kk];
            const float4 a3 = *(const float4*)&A_lds[rb + 3][kk];
            const float w0 = We[(size_t)(k0 + kk + 0) * 1024 + n];
            const float w1 = We[(size_t)(k0 + kk + 1) * 1024 + n];
            const float w2 = We[(size_t)(k0 + kk + 2) * 1024 + n];
            const float w3 = We[(size_t)(k0 + kk + 3) * 1024 + n];
            acc0 += a0.x * w0; acc0 += a0.y * w1; acc0 += a0.z * w2; acc0 += a0.w * w3;
            acc1 += a1.x * w0; acc1 += a1.y * w1; acc1 += a1.z * w2; acc1 += a1.w * w3;
            acc2 += a2.x * w0; acc2 += a2.y * w1; acc2 += a2.z * w2; acc2 += a2.w * w3;
            acc3 += a3.x * w0; acc3 += a3.y * w1; acc3 += a3.z * w2; acc3 += a3.w * w3;
        }
    }

    const float bb = be[n];
    const int orow = btile + rb;
    #pragma unroll
    for (int r = 0; r < 4; ++r) {
        const float m = (r == 0 ? acc0 : r == 1 ? acc1 : r == 2 ? acc2 : acc3) + bb;
        const size_t idx = (size_t)(orow + r) * 1024 + n;
        n_out[idx] = ft[idx] * n_prev[idx] + it[idx] * expf(m);
    }
}

// ---------------------------------------------------------------------------
// Kernel 3: per C-row (b,i):
//   C_t[b,i,j] = f[b,i]*C_prev[b,i,j] + (i[b,i]*v[b,i])*k_t[b,j]
//   h_t[b,i]   = o[b,i] * (sum_j C_t[b,i,j]*q_t[b,j]) / n_t[b,i]
// One block (256 threads) per row; each thread handles one float4 (j0=t*4).
// ---------------------------------------------------------------------------
__global__ __launch_bounds__(256) void c_update(
    const float* __restrict__ C_prev, const float* __restrict__ ws,
    const float* __restrict__ n_t, float* __restrict__ h_t,
    float* __restrict__ C_t)
{
    const int R = blockIdx.x;       // R = b*1024 + i
    const int b = R >> 10;
    const int t = threadIdx.x;

    const float f  = ws[1 * BH + R];
    const float iv = ws[0 * BH + R] * ws[4 * BH + R];
    const float o  = ws[2 * BH + R];

    const float4* kp = (const float4*)(ws + 3 * BH + (size_t)b * 1024);
    const float4* qp = (const float4*)(ws + 5 * BH + (size_t)b * 1024);
    const float4* cp = (const float4*)(C_prev + (size_t)R * 1024);
    float4*       co = (float4*)(C_t + (size_t)R * 1024);

    const float4 c4 = cp[t];
    const float4 k4 = kp[t];
    const float4 q4 = qp[t];

    float4 r;
    r.x = f * c4.x + iv * k4.x;
    r.y = f * c4.y + iv * k4.y;
    r.z = f * c4.z + iv * k4.z;
    r.w = f * c4.w + iv * k4.w;
    co[t] = r;

    float dot = r.x * q4.x + r.y * q4.y + r.z * q4.z + r.w * q4.w;

    // wave-64 shuffle reduce, then cross-wave via LDS
    #pragma unroll
    for (int off = 32; off > 0; off >>= 1)
        dot += __shfl_down(dot, off);

    __shared__ float sred[4];
    if ((t & 63) == 0) sred[t >> 6] = dot;
    __syncthreads();
    if (t == 0) {
        const float d = sred[0] + sred[1] + sred[2] + sred[3];
        h_t[R] = o * d / n_t[R];
    }
}

// ---------------------------------------------------------------------------
extern "C" void kernel_launch(void* const* d_in, const int* in_sizes, int n_in,
                              void* d_out, int out_size, void* d_ws, size_t ws_size,
                              hipStream_t stream)
{
    const float* x      = (const float*)d_in[0];
    const float* h_prev = (const float*)d_in[1];
    const float* C_prev = (const float*)d_in[2];
    const float* n_prev = (const float*)d_in[3];
    const float* Wi = (const float*)d_in[4];  const float* bi = (const float*)d_in[5];
    const float* Wf = (const float*)d_in[6];  const float* bf = (const float*)d_in[7];
    const float* Wo = (const float*)d_in[8];  const float* bo = (const float*)d_in[9];
    const float* Wk = (const float*)d_in[10]; const float* bk = (const float*)d_in[11];
    const float* Wv = (const float*)d_in[12]; const float* bv = (const float*)d_in[13];
    const float* Wq = (const float*)d_in[14]; const float* bq = (const float*)d_in[15];
    const float* We = (const float*)d_in[16]; const float* be = (const float*)d_in[17];

    float* out = (float*)d_out;
    float* h_t = out;                                    // [B,H]
    float* C_t = out + BH;                               // [B,H,H]
    float* n_t = out + BH + (size_t)Bn * Hn * Hn;        // [B,H]
    float* ws  = (float*)d_ws;                           // 6 * BH floats

    // 1) i,f,o,k,v,q
    gates_gemm<<<dim3(16, 4, 6), 256, 0, stream>>>(
        x, h_prev, Wi, bi, Wf, bf, Wo, bo, Wk, bk, Wv, bv, Wq, bq, ws);

    // 2) n_t = f*n_prev + i*exp(k@We + be)
    ngate_gemm<<<dim3(16, 4), 256, 0, stream>>>(We, be, n_prev, ws, n_t);

    // 3) C_t rows + fused h_t
    c_update<<<dim3(BH), 256, 0, stream>>>(C_prev, ws, n_t, h_t, C_t);
}

// Round 2
// 637.741 us; speedup vs baseline: 1.0320x; 1.0320x over previous
//
#include <hip/hip_runtime.h>
#include <math.h>

#define Bn 64
#define Hn 1024
#define BH 65536          // Bn * Hn

// ws layout (floats):
//   [0      , 6*BH)  : final gates i,f,o,k,v,q  (g*BH + b*1024 + n)
//   [6*BH   , 30*BH) : gate GEMM partials, (g*4 + s)*BH
//   [30*BH  , 34*BH) : ngate GEMM partials, s*BH
#define WS_GP (6 * BH)
#define WS_NP (30 * BH)

// ---------------------------------------------------------------------------
// Kernel A: partial GEMMs for the six projections.
//   grid = (16 n-tiles, 4 K-splits, 6 gates), block = 256.
//   Each block computes all 64 B-rows x 64 cols for 1/4 of K (no bias/act).
//   Weights are read exactly once across the whole grid (no b-tile redundancy).
//   Thread: 2 cols (t&31, +32) x 8 rows (rg = t>>5) -> each LDS b128 A-read
//   feeds 8 FMAs.
// ---------------------------------------------------------------------------
__global__ __launch_bounds__(256) void gates_partial(
    const float* __restrict__ x, const float* __restrict__ h_prev,
    const float* __restrict__ Wi, const float* __restrict__ Wf,
    const float* __restrict__ Wo, const float* __restrict__ Wk,
    const float* __restrict__ Wv, const float* __restrict__ Wq,
    float* __restrict__ ws)
{
    const int g = blockIdx.z, s = blockIdx.y;
    const float* Wm;
    int Ktot;
    switch (g) {
        case 0: Wm = Wi; Ktot = 2048; break;
        case 1: Wm = Wf; Ktot = 2048; break;
        case 2: Wm = Wo; Ktot = 2048; break;
        case 3: Wm = Wk; Ktot = 1024; break;
        case 4: Wm = Wv; Ktot = 1024; break;
        default: Wm = Wq; Ktot = 1024; break;
    }
    const int chunk = Ktot >> 2;      // 512 or 256
    const int kbase = s * chunk;

    __shared__ float A_lds[64][64];   // 16 KB

    const int t  = threadIdx.x;
    const int n0 = (blockIdx.x << 6) + (t & 31);
    const int n1 = n0 + 32;
    const int rg = t >> 5;            // 0..7 -> rows rg*8 .. rg*8+7

    float acc0[8], acc1[8];
    #pragma unroll
    for (int r = 0; r < 8; ++r) { acc0[r] = 0.f; acc1[r] = 0.f; }

    for (int kc = 0; kc < chunk; kc += 64) {
        const int k0 = kbase + kc;
        const float* Ab;
        int kloc;
        if (g < 3)       { Ab = (k0 < 1024) ? x : h_prev; kloc = k0 & 1023; }
        else if (g == 5) { Ab = h_prev; kloc = k0; }
        else             { Ab = x;      kloc = k0; }

        __syncthreads();
        {   // cooperative stage: 64 rows x 64 k-cols
            const int c     = (t & 15) << 2;
            const int rbase = t >> 4;
            #pragma unroll
            for (int rr = 0; rr < 4; ++rr) {
                const int row = rbase + (rr << 4);
                *(float4*)&A_lds[row][c] =
                    *(const float4*)&Ab[(size_t)row * 1024 + kloc + c];
            }
        }
        __syncthreads();

        #pragma unroll 4
        for (int kk = 0; kk < 64; kk += 4) {
            const size_t wb = (size_t)(k0 + kk) * 1024;
            const float w00 = Wm[wb          + n0], w01 = Wm[wb          + n1];
            const float w10 = Wm[wb + 1024   + n0], w11 = Wm[wb + 1024   + n1];
            const float w20 = Wm[wb + 2048   + n0], w21 = Wm[wb + 2048   + n1];
            const float w30 = Wm[wb + 3072   + n0], w31 = Wm[wb + 3072   + n1];
            #pragma unroll
            for (int r = 0; r < 8; ++r) {
                const float4 a = *(const float4*)&A_lds[rg * 8 + r][kk];
                acc0[r] += a.x * w00 + a.y * w10 + a.z * w20 + a.w * w30;
                acc1[r] += a.x * w01 + a.y * w11 + a.z * w21 + a.w * w31;
            }
        }
    }

    float* P = ws + WS_GP + (size_t)(g * 4 + s) * BH;
    #pragma unroll
    for (int r = 0; r < 8; ++r) {
        const int row = rg * 8 + r;
        P[(size_t)row * 1024 + n0] = acc0[r];
        P[(size_t)row * 1024 + n1] = acc1[r];
    }
}

// ---------------------------------------------------------------------------
// Kernel B: reduce 4 K-split partials + bias (+ sigmoid for i,f,o) -> ws gates
// ---------------------------------------------------------------------------
__global__ __launch_bounds__(256) void gates_finalize(
    const float* __restrict__ bi, const float* __restrict__ bf,
    const float* __restrict__ bo, const float* __restrict__ bk,
    const float* __restrict__ bv, const float* __restrict__ bq,
    float* __restrict__ ws)
{
    const int id = blockIdx.x * 256 + threadIdx.x;   // < 6*BH
    const int g  = id >> 16;                          // BH == 65536
    const int r  = id & 0xFFFF;
    const int n  = r & 1023;
    const float* P = ws + WS_GP + (size_t)g * 4 * BH;
    float v = P[r] + P[BH + r] + P[2 * BH + r] + P[3 * BH + r];
    const float* bias;
    switch (g) {
        case 0: bias = bi; break; case 1: bias = bf; break;
        case 2: bias = bo; break; case 3: bias = bk; break;
        case 4: bias = bv; break; default: bias = bq; break;
    }
    v += bias[n];
    if (g < 3) v = 1.f / (1.f + expf(-v));
    ws[(size_t)g * BH + r] = v;
}

// ---------------------------------------------------------------------------
// Kernel C: partials of m = k_t @ We   (k_t read from ws). grid (16, 4).
// ---------------------------------------------------------------------------
__global__ __launch_bounds__(256) void ngate_partial(
    const float* __restrict__ We, const float* __restrict__ ws_in,
    float* __restrict__ ws)
{
    const int s = blockIdx.y;
    const int chunk = 256;
    const int kbase = s * chunk;
    const float* kt = ws_in + 3 * BH;

    __shared__ float A_lds[64][64];

    const int t  = threadIdx.x;
    const int n0 = (blockIdx.x << 6) + (t & 31);
    const int n1 = n0 + 32;
    const int rg = t >> 5;

    float acc0[8], acc1[8];
    #pragma unroll
    for (int r = 0; r < 8; ++r) { acc0[r] = 0.f; acc1[r] = 0.f; }

    for (int kc = 0; kc < chunk; kc += 64) {
        const int k0 = kbase + kc;
        __syncthreads();
        {
            const int c     = (t & 15) << 2;
            const int rbase = t >> 4;
            #pragma unroll
            for (int rr = 0; rr < 4; ++rr) {
                const int row = rbase + (rr << 4);
                *(float4*)&A_lds[row][c] =
                    *(const float4*)&kt[(size_t)row * 1024 + k0 + c];
            }
        }
        __syncthreads();

        #pragma unroll 4
        for (int kk = 0; kk < 64; kk += 4) {
            const size_t wb = (size_t)(k0 + kk) * 1024;
            const float w00 = We[wb          + n0], w01 = We[wb          + n1];
            const float w10 = We[wb + 1024   + n0], w11 = We[wb + 1024   + n1];
            const float w20 = We[wb + 2048   + n0], w21 = We[wb + 2048   + n1];
            const float w30 = We[wb + 3072   + n0], w31 = We[wb + 3072   + n1];
            #pragma unroll
            for (int r = 0; r < 8; ++r) {
                const float4 a = *(const float4*)&A_lds[rg * 8 + r][kk];
                acc0[r] += a.x * w00 + a.y * w10 + a.z * w20 + a.w * w30;
                acc1[r] += a.x * w01 + a.y * w11 + a.z * w21 + a.w * w31;
            }
        }
    }

    float* P = ws + WS_NP + (size_t)s * BH;
    #pragma unroll
    for (int r = 0; r < 8; ++r) {
        const int row = rg * 8 + r;
        P[(size_t)row * 1024 + n0] = acc0[r];
        P[(size_t)row * 1024 + n1] = acc1[r];
    }
}

// ---------------------------------------------------------------------------
// Kernel D: n_t = f*n_prev + i*exp(m + be)
// ---------------------------------------------------------------------------
__global__ __launch_bounds__(256) void ngate_finalize(
    const float* __restrict__ be, const float* __restrict__ n_prev,
    const float* __restrict__ ws, float* __restrict__ n_out)
{
    const int id = blockIdx.x * 256 + threadIdx.x;   // < BH
    const float* P = ws + WS_NP;
    const float m = P[id] + P[BH + id] + P[2 * BH + id] + P[3 * BH + id]
                  + be[id & 1023];
    n_out[id] = ws[BH + id] * n_prev[id] + ws[id] * expf(m);
}

// ---------------------------------------------------------------------------
// Kernel E: C update + fused h_t. One WAVE per row, 8 rows/wave, 32 rows/block
// (all rows of a block share b, so k,q live in registers). No __syncthreads.
//   C_t[R,j] = f[R]*C_prev[R,j] + (i[R]*v[R])*k[b,j]
//   h_t[R]   = o[R] * (C_t[R,:] . q[b,:]) / n_t[R]
// ---------------------------------------------------------------------------
__global__ __launch_bounds__(256) void c_update(
    const float* __restrict__ C_prev, const float* __restrict__ ws,
    const float* __restrict__ n_t, float* __restrict__ h_t,
    float* __restrict__ C_t)
{
    const int t    = threadIdx.x;
    const int lane = t & 63;
    const int w    = t >> 6;                       // wave 0..3
    const int R0   = blockIdx.x * 32 + w * 8;      // first of 8 rows
    const int b    = R0 >> 10;

    const float4* kp = (const float4*)(ws + 3 * BH + (size_t)b * 1024);
    const float4* qp = (const float4*)(ws + 5 * BH + (size_t)b * 1024);
    float4 k4[4], q4[4];
    #pragma unroll
    for (int c = 0; c < 4; ++c) {
        k4[c] = kp[c * 64 + lane];
        q4[c] = qp[c * 64 + lane];
    }

    #pragma unroll 2
    for (int r = 0; r < 8; ++r) {
        const int R    = R0 + r;
        const float f  = ws[1 * BH + R];
        const float iv = ws[0 * BH + R] * ws[4 * BH + R];
        const float4* cp = (const float4*)(C_prev + (size_t)R * 1024);
        float4*       co = (float4*)(C_t + (size_t)R * 1024);

        float dot = 0.f;
        #pragma unroll
        for (int c = 0; c < 4; ++c) {
            const float4 c4 = cp[c * 64 + lane];
            float4 o4;
            o4.x = f * c4.x + iv * k4[c].x;
            o4.y = f * c4.y + iv * k4[c].y;
            o4.z = f * c4.z + iv * k4[c].z;
            o4.w = f * c4.w + iv * k4[c].w;
            co[c * 64 + lane] = o4;
            dot += o4.x * q4[c].x + o4.y * q4[c].y
                 + o4.z * q4[c].z + o4.w * q4[c].w;
        }
        #pragma unroll
        for (int off = 32; off; off >>= 1)
            dot += __shfl_xor(dot, off);
        if (lane == 0)
            h_t[R] = ws[2 * BH + R] * dot / n_t[R];
    }
}

// ---------------------------------------------------------------------------
extern "C" void kernel_launch(void* const* d_in, const int* in_sizes, int n_in,
                              void* d_out, int out_size, void* d_ws, size_t ws_size,
                              hipStream_t stream)
{
    const float* x      = (const float*)d_in[0];
    const float* h_prev = (const float*)d_in[1];
    const float* C_prev = (const float*)d_in[2];
    const float* n_prev = (const float*)d_in[3];
    const float* Wi = (const float*)d_in[4];  const float* bi = (const float*)d_in[5];
    const float* Wf = (const float*)d_in[6];  const float* bf = (const float*)d_in[7];
    const float* Wo = (const float*)d_in[8];  const float* bo = (const float*)d_in[9];
    const float* Wk = (const float*)d_in[10]; const float* bk = (const float*)d_in[11];
    const float* Wv = (const float*)d_in[12]; const float* bv = (const float*)d_in[13];
    const float* Wq = (const float*)d_in[14]; const float* bq = (const float*)d_in[15];
    const float* We = (const float*)d_in[16]; const float* be = (const float*)d_in[17];

    float* out = (float*)d_out;
    float* h_t = out;                                 // [B,H]
    float* C_t = out + BH;                            // [B,H,H]
    float* n_t = out + BH + (size_t)Bn * Hn * Hn;     // [B,H]
    float* ws  = (float*)d_ws;                        // 34*BH floats (~8.9 MB)

    gates_partial<<<dim3(16, 4, 6), 256, 0, stream>>>(
        x, h_prev, Wi, Wf, Wo, Wk, Wv, Wq, ws);

    gates_finalize<<<(6 * BH) / 256, 256, 0, stream>>>(
        bi, bf, bo, bk, bv, bq, ws);

    ngate_partial<<<dim3(16, 4), 256, 0, stream>>>(We, ws, ws);

    ngate_finalize<<<BH / 256, 256, 0, stream>>>(be, n_prev, ws, n_t);

    c_update<<<2048, 256, 0, stream>>>(C_prev, ws, n_t, h_t, C_t);
}